// Round 1
// baseline (7175.723 us; speedup 1.0000x reference)
//
#include <hip/hip_runtime.h>
#include <hip/hip_bf16.h>

#define B_ROWS 16384
#define U_DIM  128
#define H_DIM  512
#define R_TILE 16
#define DT_F     0.1f
#define LN_EPS_F 1e-3f

// f(x) = LN(x@W1+b1)*gamma+beta -> ReLU -> @W2+b2
// One block handles R_TILE=16 rows with 256 threads.
// WRITE_OUT: write f(x) to OUT.  DO_REG: compute sum of softmax-weighted
// |f(x)| row norms into regPart[segIdx*gridDim.x + blockIdx.x].
template<bool WRITE_OUT, bool DO_REG>
__global__ __launch_bounds__(256)
void f_eval(const float* __restrict__ X, const float* __restrict__ K, float c,
            float* __restrict__ OUT,
            const float* __restrict__ W1, const float* __restrict__ b1,
            const float* __restrict__ gamma, const float* __restrict__ beta,
            const float* __restrict__ W2, const float* __restrict__ b2,
            float* __restrict__ regPart, int segIdx)
{
    __shared__ float x_lds[R_TILE][U_DIM];        // 8 KB; reused as |out| tile in DO_REG
    __shared__ float h_lds[R_TILE][H_DIM + 4];    // 33 KB, +4 pad keeps 16B align & breaks bank repeat
    __shared__ float mu_s[R_TILE], rs_s[R_TILE];
    __shared__ float norms[R_TILE];

    const int t    = threadIdx.x;
    const int row0 = blockIdx.x * R_TILE;

    // ---- Phase 0: x_in = X + c*K, stage tile in LDS ----
    #pragma unroll
    for (int i = 0; i < (R_TILE * U_DIM) / 256; ++i) {   // 8
        int idx = i * 256 + t;
        int r = idx >> 7, u = idx & 127;
        int g = (row0 + r) * U_DIM + u;
        float v = X[g];
        if (c != 0.0f) v = fmaf(c, K[g], v);
        x_lds[r][u] = v;
    }
    __syncthreads();

    // ---- Phase 1: h = x @ W1 + b1; thread t owns columns t and t+256 ----
    float acc0[R_TILE], acc1[R_TILE];
    {
        float bb0 = b1[t], bb1 = b1[t + 256];
        #pragma unroll
        for (int r = 0; r < R_TILE; ++r) { acc0[r] = bb0; acc1[r] = bb1; }
    }
    for (int k = 0; k < U_DIM; k += 4) {
        float4 xv[R_TILE];
        #pragma unroll
        for (int r = 0; r < R_TILE; ++r)
            xv[r] = *reinterpret_cast<const float4*>(&x_lds[r][k]);
        #pragma unroll
        for (int kk = 0; kk < 4; ++kk) {
            float w0 = W1[(k + kk) * H_DIM + t];
            float w1 = W1[(k + kk) * H_DIM + 256 + t];
            #pragma unroll
            for (int r = 0; r < R_TILE; ++r) {
                float xr = (&xv[r].x)[kk];
                acc0[r] = fmaf(xr, w0, acc0[r]);
                acc1[r] = fmaf(xr, w1, acc1[r]);
            }
        }
    }
    #pragma unroll
    for (int r = 0; r < R_TILE; ++r) {
        h_lds[r][t]       = acc0[r];
        h_lds[r][t + 256] = acc1[r];
    }
    __syncthreads();

    // ---- LayerNorm stats: row r handled by 16-lane group ----
    {
        int r = t >> 4, ti = t & 15;
        float s1 = 0.f, s2 = 0.f;
        #pragma unroll
        for (int i = 0; i < H_DIM / 16; ++i) {           // 32
            float v = h_lds[r][ti + 16 * i];
            s1 += v; s2 = fmaf(v, v, s2);
        }
        #pragma unroll
        for (int m = 1; m < 16; m <<= 1) {
            s1 += __shfl_xor(s1, m);
            s2 += __shfl_xor(s2, m);
        }
        if (ti == 0) {
            float mu  = s1 * (1.0f / H_DIM);
            float var = s2 * (1.0f / H_DIM) - mu * mu;
            mu_s[r] = mu;
            rs_s[r] = rsqrtf(var + LN_EPS_F);
        }
    }
    __syncthreads();

    // ---- Apply LN + ReLU in place ----
    #pragma unroll
    for (int i = 0; i < (R_TILE * H_DIM) / 256; ++i) {   // 32
        int idx = i * 256 + t;
        int r = idx >> 9, j = idx & 511;
        float v = h_lds[r][j];
        v = fmaf((v - mu_s[r]) * rs_s[r], gamma[j], beta[j]);
        h_lds[r][j] = fmaxf(v, 0.f);
    }
    __syncthreads();

    // ---- Phase 2: out = h @ W2 + b2; thread t owns col u=t&127, rows rg*8..rg*8+7 ----
    const int u  = t & 127;
    const int rg = t >> 7;
    float acc2[8];
    {
        float bb = b2[u];
        #pragma unroll
        for (int i = 0; i < 8; ++i) acc2[i] = bb;
    }
    for (int j = 0; j < H_DIM; j += 4) {
        float4 hv[8];
        #pragma unroll
        for (int i = 0; i < 8; ++i)
            hv[i] = *reinterpret_cast<const float4*>(&h_lds[rg * 8 + i][j]);
        #pragma unroll
        for (int jj = 0; jj < 4; ++jj) {
            float w = W2[(j + jj) * U_DIM + u];
            #pragma unroll
            for (int i = 0; i < 8; ++i)
                acc2[i] = fmaf((&hv[i].x)[jj], w, acc2[i]);
        }
    }

    if (WRITE_OUT) {
        #pragma unroll
        for (int i = 0; i < 8; ++i)
            OUT[(row0 + rg * 8 + i) * U_DIM + u] = acc2[i];
    }

    if (DO_REG) {
        // a = |out|; per-row softmax-weighted norm, then block partial sum.
        #pragma unroll
        for (int i = 0; i < 8; ++i)
            x_lds[rg * 8 + i][u] = fabsf(acc2[i]);
        __syncthreads();

        int r = t >> 4, ti = t & 15;
        float av[8], amax = -3.402823e38f;
        #pragma unroll
        for (int i = 0; i < 8; ++i) {
            av[i] = x_lds[r][ti + 16 * i];
            amax = fmaxf(amax, av[i]);
        }
        #pragma unroll
        for (int m = 1; m < 16; m <<= 1) amax = fmaxf(amax, __shfl_xor(amax, m));
        float se = 0.f, sae = 0.f;
        #pragma unroll
        for (int i = 0; i < 8; ++i) {
            float e = expf(av[i] - amax);
            se += e; sae = fmaf(av[i], e, sae);
        }
        #pragma unroll
        for (int m = 1; m < 16; m <<= 1) {
            se  += __shfl_xor(se, m);
            sae += __shfl_xor(sae, m);
        }
        if (ti == 0) norms[r] = sae / se;
        __syncthreads();
        if (t == 0) {
            float s = 0.f;
            #pragma unroll
            for (int r2 = 0; r2 < R_TILE; ++r2) s += norms[r2];
            regPart[segIdx * gridDim.x + blockIdx.x] = s;
        }
    }
}

// X += dt/6 * (K1 + 2*K2 + 2*K3 + K4), vectorized
__global__ __launch_bounds__(256)
void rk4_combine(float4* __restrict__ X,
                 const float4* __restrict__ K1, const float4* __restrict__ K2,
                 const float4* __restrict__ K3, const float4* __restrict__ K4)
{
    int i = blockIdx.x * 256 + threadIdx.x;
    const float w = DT_F / 6.0f;
    float4 x = X[i], a = K1[i], b = K2[i], c3 = K3[i], d = K4[i];
    x.x = fmaf(w, a.x + 2.f * b.x + 2.f * c3.x + d.x, x.x);
    x.y = fmaf(w, a.y + 2.f * b.y + 2.f * c3.y + d.y, x.y);
    x.z = fmaf(w, a.z + 2.f * b.z + 2.f * c3.z + d.z, x.z);
    x.w = fmaf(w, a.w + 2.f * b.w + 2.f * c3.w + d.w, x.w);
    X[i] = x;
}

// Deterministic reduction of 5*1024 block partials -> regularization scalar
__global__ __launch_bounds__(256)
void finalize_reg(const float* __restrict__ part, float* __restrict__ out)
{
    __shared__ float wsum[4];
    int t = threadIdx.x;
    float s = 0.f;
    for (int i = t; i < 5 * (B_ROWS / R_TILE); i += 256) s += part[i];
    #pragma unroll
    for (int m = 1; m < 64; m <<= 1) s += __shfl_xor(s, m);
    if ((t & 63) == 0) wsum[t >> 6] = s;
    __syncthreads();
    if (t == 0)
        out[0] = (wsum[0] + wsum[1] + wsum[2] + wsum[3]) / (5.0f * (float)B_ROWS);
}

extern "C" void kernel_launch(void* const* d_in, const int* in_sizes, int n_in,
                              void* d_out, int out_size, void* d_ws, size_t ws_size,
                              hipStream_t stream)
{
    const float* x0    = (const float*)d_in[0];
    const float* W1    = (const float*)d_in[1];
    const float* b1    = (const float*)d_in[2];
    const float* gamma = (const float*)d_in[3];
    const float* beta  = (const float*)d_in[4];
    const float* W2    = (const float*)d_in[5];
    const float* b2    = (const float*)d_in[6];
    float* out = (float*)d_out;

    const size_t nX = (size_t)B_ROWS * U_DIM;     // 2097152
    float* X  = (float*)d_ws;
    float* K1 = X  + nX;
    float* K2 = K1 + nX;
    float* K3 = K2 + nX;
    float* K4 = K3 + nX;
    float* regPart = K4 + nX;                     // 5*1024 floats

    hipMemcpyAsync(X, x0, nX * sizeof(float), hipMemcpyDeviceToDevice, stream);

    dim3 grid(B_ROWS / R_TILE), blk(256);
    dim3 cgrid(nX / 4 / 256);
    int seg = 0;
    for (int s = 0; s < 20; ++s) {
        f_eval<true, false><<<grid, blk, 0, stream>>>(X, X,  0.0f,        K1, W1, b1, gamma, beta, W2, b2, nullptr, 0);
        f_eval<true, false><<<grid, blk, 0, stream>>>(X, K1, 0.5f * DT_F, K2, W1, b1, gamma, beta, W2, b2, nullptr, 0);
        f_eval<true, false><<<grid, blk, 0, stream>>>(X, K2, 0.5f * DT_F, K3, W1, b1, gamma, beta, W2, b2, nullptr, 0);
        f_eval<true, false><<<grid, blk, 0, stream>>>(X, K3, DT_F,        K4, W1, b1, gamma, beta, W2, b2, nullptr, 0);
        rk4_combine<<<cgrid, blk, 0, stream>>>((float4*)X, (const float4*)K1, (const float4*)K2,
                                               (const float4*)K3, (const float4*)K4);
        if (s >= 10 && (s & 1)) {   // after 1-indexed steps 12,14,16,18,20: x == xs[seg]
            f_eval<false, true><<<grid, blk, 0, stream>>>(X, X, 0.0f, nullptr, W1, b1, gamma, beta, W2, b2, regPart, seg);
            ++seg;
        }
    }

    hipMemcpyAsync(out, X, nX * sizeof(float), hipMemcpyDeviceToDevice, stream);
    finalize_reg<<<1, blk, 0, stream>>>(regPart, out + nX);
}

// Round 2
// 2450.138 us; speedup vs baseline: 2.9287x; 2.9287x over previous
//
#include <hip/hip_runtime.h>
#include <hip/hip_bf16.h>

typedef short bf16x8 __attribute__((ext_vector_type(8)));
typedef float f32x4  __attribute__((ext_vector_type(4)));
typedef unsigned short ushort_t;

#define DT_F     0.1f
#define LN_EPS_F 1e-3f

__device__ __forceinline__ ushort_t f2bf(float v) {
    union { float f; unsigned u; } x; x.f = v;
    unsigned r = x.u + 0x7fffu + ((x.u >> 16) & 1u);   // round-to-nearest-even
    return (ushort_t)(r >> 16);
}
__device__ __forceinline__ float bf2f(ushort_t h) {
    union { unsigned u; float f; } y; y.u = ((unsigned)h) << 16;
    return y.f;
}

// ---------------------------------------------------------------------------
// Pack W1 (128x512) and W2 (512x128) into MFMA A-fragment order (swapped GEMM:
// A = W^T), bf16 hi/lo split, with k-permutation pi(ks,g,j)=16*(2ks+(j>>2))+4g+(j&3).
// W1pack: [mh 32][ku 4][hl 2][lane 64][8 bf16]   W2pack: [mu2 8][kh 16][hl 2][lane][8]
// ---------------------------------------------------------------------------
__global__ __launch_bounds__(256)
void pack_weights(const float* __restrict__ W1, const float* __restrict__ W2,
                  ushort_t* __restrict__ w1p, ushort_t* __restrict__ w2p)
{
    int tid  = blockIdx.x * 256 + threadIdx.x;   // 0..16383
    int lane = tid & 63;
    int g = lane >> 4, l15 = lane & 15;
    int fi = tid >> 6;                            // 0..255
    bf16x8 hi, lo;
    if (fi < 128) {
        int mh = fi >> 2, ku = fi & 3;
        #pragma unroll
        for (int j = 0; j < 8; ++j) {
            int u = 16 * (2 * ku + (j >> 2)) + 4 * g + (j & 3);
            float v = W1[u * 512 + 16 * mh + l15];
            ushort_t h = f2bf(v);
            hi[j] = (short)h;
            lo[j] = (short)f2bf(v - bf2f(h));
        }
        bf16x8* w1v = (bf16x8*)w1p;
        w1v[((fi * 2 + 0) * 64) + lane] = hi;
        w1v[((fi * 2 + 1) * 64) + lane] = lo;
    } else {
        int fj = fi - 128;
        int mu2 = fj >> 4, kh = fj & 15;
        #pragma unroll
        for (int j = 0; j < 8; ++j) {
            int hr = 16 * (2 * kh + (j >> 2)) + 4 * g + (j & 3);
            float v = W2[hr * 128 + 16 * mu2 + l15];
            ushort_t h = f2bf(v);
            hi[j] = (short)h;
            lo[j] = (short)f2bf(v - bf2f(h));
        }
        bf16x8* w2v = (bf16x8*)w2p;
        w2v[((fj * 2 + 0) * 64) + lane] = hi;
        w2v[((fj * 2 + 1) * 64) + lane] = lo;
    }
}

// ---------------------------------------------------------------------------
// Persistent ODE kernel: 256 blocks x 256 threads; block owns 64 batch rows.
// All 20 RK4 steps + 5 regularization evals in-kernel (rows are independent).
// ---------------------------------------------------------------------------
__global__ __launch_bounds__(256, 1)
void node_ode(const float* __restrict__ x0,
              const float* __restrict__ gamma, const float* __restrict__ beta,
              const float* __restrict__ b1,    const float* __restrict__ b2,
              const ushort_t* __restrict__ w1p, const ushort_t* __restrict__ w2p,
              float* __restrict__ out, float* __restrict__ regPart)
{
    extern __shared__ char smem[];
    ushort_t* xinh = (ushort_t*)smem;              // [4nb][4ku][64][8]  16 KB
    ushort_t* xinl = (ushort_t*)(smem + 16384);    // 16 KB
    ushort_t* hbuf = (ushort_t*)(smem + 32768);    // [16kh][4nb][64][8] 64 KB
    float*    gbuf = (float*)(smem + 98304);       // [512][{gamma,beta}] 4 KB
    float*    b1b  = (float*)(smem + 102400);      // 2 KB
    float*    b2b  = (float*)(smem + 104448);      // 512 B
    float*    lnb  = (float*)(smem + 104960);      // [4w][4nb][16][2] 2 KB
    float*    rmx  = (float*)(smem + 107008);      // [4w][4nb][16] 1 KB
    // total 108032 B

    const int t = threadIdx.x, lane = t & 63, w = t >> 6;
    const int g = lane >> 4, l15 = lane & 15;
    const int row0 = blockIdx.x * 64;

    const bf16x8* w1v = (const bf16x8*)w1p;
    const bf16x8* w2v = (const bf16x8*)w2p;

    for (int c = t; c < 512; c += 256) {
        gbuf[2 * c] = gamma[c]; gbuf[2 * c + 1] = beta[c]; b1b[c] = b1[c];
    }
    if (t < 128) b2b[t] = b2[t];

    // x state in registers: xreg[p][nb] covers rows 16nb+l15, ucols 16*(2w+p)+4g+r
    f32x4 xreg[2][4], acck[2][4], kreg[2][4];
    #pragma unroll
    for (int p = 0; p < 2; ++p)
        #pragma unroll
        for (int nb = 0; nb < 4; ++nb) {
            int brow = row0 + 16 * nb + l15;
            int ucol = 16 * (2 * w + p) + 4 * g;
            xreg[p][nb] = *(const f32x4*)&x0[brow * 128 + ucol];
            kreg[p][nb] = (f32x4)0.0f;
        }
    __syncthreads();

    float regtot = 0.0f;

    auto build_xin = [&](float c) {
        #pragma unroll
        for (int p = 0; p < 2; ++p)
            #pragma unroll
            for (int nb = 0; nb < 4; ++nb) {
                f32x4 xv = xreg[p][nb];
                if (c != 0.0f) xv += kreg[p][nb] * c;
                unsigned h01, h23, l01, l23;
                {
                    ushort_t h0 = f2bf(xv[0]), h1 = f2bf(xv[1]), h2 = f2bf(xv[2]), h3 = f2bf(xv[3]);
                    ushort_t q0 = f2bf(xv[0] - bf2f(h0)), q1 = f2bf(xv[1] - bf2f(h1));
                    ushort_t q2 = f2bf(xv[2] - bf2f(h2)), q3 = f2bf(xv[3] - bf2f(h3));
                    h01 = (unsigned)h0 | ((unsigned)h1 << 16);
                    h23 = (unsigned)h2 | ((unsigned)h3 << 16);
                    l01 = (unsigned)q0 | ((unsigned)q1 << 16);
                    l23 = (unsigned)q2 | ((unsigned)q3 << 16);
                }
                int off = ((nb * 4 + w) * 64 + lane) * 8 + p * 4;   // ku slot = w, half = p
                *reinterpret_cast<uint2*>(&xinh[off]) = make_uint2(h01, h23);
                *reinterpret_cast<uint2*>(&xinl[off]) = make_uint2(l01, l23);
            }
    };

    // mm1 (C1^T = W1^T x^T) + LayerNorm + ReLU -> hbuf (bf16)
    auto do_mm1_ln = [&]() {
        f32x4 acc[8][4];
        #pragma unroll
        for (int mhi = 0; mhi < 8; ++mhi) {
            int mh = 8 * w + mhi;
            f32x4 bv = *(const f32x4*)&b1b[16 * mh + 4 * g];
            #pragma unroll
            for (int nb = 0; nb < 4; ++nb) acc[mhi][nb] = bv;
        }
        for (int ku = 0; ku < 4; ++ku) {
            bf16x8 Bh[4], Bl[4];
            #pragma unroll
            for (int nb = 0; nb < 4; ++nb) {
                int off = ((nb * 4 + ku) * 64 + lane) * 8;
                Bh[nb] = *(const bf16x8*)&xinh[off];
                Bl[nb] = *(const bf16x8*)&xinl[off];
            }
            #pragma unroll
            for (int mhi = 0; mhi < 8; ++mhi) {
                int mh = 8 * w + mhi;
                bf16x8 Ah = w1v[((mh * 4 + ku) * 2 + 0) * 64 + lane];
                bf16x8 Al = w1v[((mh * 4 + ku) * 2 + 1) * 64 + lane];
                #pragma unroll
                for (int nb = 0; nb < 4; ++nb)
                    acc[mhi][nb] = __builtin_amdgcn_mfma_f32_16x16x32_bf16(Ah, Bh[nb], acc[mhi][nb], 0, 0, 0);
                #pragma unroll
                for (int nb = 0; nb < 4; ++nb)
                    acc[mhi][nb] = __builtin_amdgcn_mfma_f32_16x16x32_bf16(Ah, Bl[nb], acc[mhi][nb], 0, 0, 0);
                #pragma unroll
                for (int nb = 0; nb < 4; ++nb)
                    acc[mhi][nb] = __builtin_amdgcn_mfma_f32_16x16x32_bf16(Al, Bh[nb], acc[mhi][nb], 0, 0, 0);
            }
        }
        // LayerNorm stats: rows = 16nb+l15; this wave holds 128 of 512 cols
        float s1[4] = {0,0,0,0}, s2[4] = {0,0,0,0};
        #pragma unroll
        for (int nb = 0; nb < 4; ++nb)
            #pragma unroll
            for (int mhi = 0; mhi < 8; ++mhi)
                #pragma unroll
                for (int r = 0; r < 4; ++r) {
                    float v = acc[mhi][nb][r];
                    s1[nb] += v; s2[nb] = fmaf(v, v, s2[nb]);
                }
        #pragma unroll
        for (int nb = 0; nb < 4; ++nb) {
            s1[nb] += __shfl_xor(s1[nb], 16); s1[nb] += __shfl_xor(s1[nb], 32);
            s2[nb] += __shfl_xor(s2[nb], 16); s2[nb] += __shfl_xor(s2[nb], 32);
        }
        if (lane < 16) {
            #pragma unroll
            for (int nb = 0; nb < 4; ++nb) {
                lnb[((w * 4 + nb) * 16 + l15) * 2 + 0] = s1[nb];
                lnb[((w * 4 + nb) * 16 + l15) * 2 + 1] = s2[nb];
            }
        }
        __syncthreads();
        float mu_[4], rs_[4];
        #pragma unroll
        for (int nb = 0; nb < 4; ++nb) {
            float t1 = 0.f, t2 = 0.f;
            #pragma unroll
            for (int ww = 0; ww < 4; ++ww) {
                t1 += lnb[((ww * 4 + nb) * 16 + l15) * 2 + 0];
                t2 += lnb[((ww * 4 + nb) * 16 + l15) * 2 + 1];
            }
            float m = t1 * (1.0f / 512.0f);
            float var = t2 * (1.0f / 512.0f) - m * m;
            mu_[nb] = m; rs_[nb] = rsqrtf(var + LN_EPS_F);
        }
        // apply LN * gamma + beta, ReLU, bf16, write hbuf
        #pragma unroll
        for (int mhi = 0; mhi < 8; ++mhi) {
            int mh = 8 * w + mhi;
            float2 gp[4];
            #pragma unroll
            for (int r = 0; r < 4; ++r) gp[r] = *(const float2*)&gbuf[(16 * mh + 4 * g + r) * 2];
            #pragma unroll
            for (int nb = 0; nb < 4; ++nb) {
                unsigned q01, q23;
                {
                    float v0 = fmaxf(fmaf((acc[mhi][nb][0] - mu_[nb]) * rs_[nb], gp[0].x, gp[0].y), 0.f);
                    float v1 = fmaxf(fmaf((acc[mhi][nb][1] - mu_[nb]) * rs_[nb], gp[1].x, gp[1].y), 0.f);
                    float v2 = fmaxf(fmaf((acc[mhi][nb][2] - mu_[nb]) * rs_[nb], gp[2].x, gp[2].y), 0.f);
                    float v3 = fmaxf(fmaf((acc[mhi][nb][3] - mu_[nb]) * rs_[nb], gp[3].x, gp[3].y), 0.f);
                    q01 = (unsigned)f2bf(v0) | ((unsigned)f2bf(v1) << 16);
                    q23 = (unsigned)f2bf(v2) | ((unsigned)f2bf(v3) << 16);
                }
                int off = (((mh >> 1) * 4 + nb) * 64 + lane) * 8 + (mh & 1) * 4;
                *reinterpret_cast<uint2*>(&hbuf[off]) = make_uint2(q01, q23);
            }
        }
    };

    // mm2 (out^T = W2^T h^T) -> kreg
    auto do_mm2 = [&]() {
        #pragma unroll
        for (int p = 0; p < 2; ++p) {
            f32x4 bv = *(const f32x4*)&b2b[16 * (2 * w + p) + 4 * g];
            #pragma unroll
            for (int nb = 0; nb < 4; ++nb) kreg[p][nb] = bv;
        }
        for (int kh = 0; kh < 16; ++kh) {
            bf16x8 Bf[4];
            #pragma unroll
            for (int nb = 0; nb < 4; ++nb)
                Bf[nb] = *(const bf16x8*)&hbuf[((kh * 4 + nb) * 64 + lane) * 8];
            bf16x8 Ah[2], Al[2];
            #pragma unroll
            for (int p = 0; p < 2; ++p) {
                int mu2 = 2 * w + p;
                Ah[p] = w2v[((mu2 * 16 + kh) * 2 + 0) * 64 + lane];
                Al[p] = w2v[((mu2 * 16 + kh) * 2 + 1) * 64 + lane];
            }
            #pragma unroll
            for (int p = 0; p < 2; ++p)
                #pragma unroll
                for (int nb = 0; nb < 4; ++nb)
                    kreg[p][nb] = __builtin_amdgcn_mfma_f32_16x16x32_bf16(Ah[p], Bf[nb], kreg[p][nb], 0, 0, 0);
            #pragma unroll
            for (int p = 0; p < 2; ++p)
                #pragma unroll
                for (int nb = 0; nb < 4; ++nb)
                    kreg[p][nb] = __builtin_amdgcn_mfma_f32_16x16x32_bf16(Al[p], Bf[nb], kreg[p][nb], 0, 0, 0);
        }
    };

    auto f_eval = [&](float c) {
        build_xin(c);
        __syncthreads();
        do_mm1_ln();
        __syncthreads();
        do_mm2();
    };

    for (int s = 0; s < 20; ++s) {
        #pragma unroll
        for (int p = 0; p < 2; ++p)
            #pragma unroll
            for (int nb = 0; nb < 4; ++nb) acck[p][nb] = (f32x4)0.0f;

        f_eval(0.0f);
        #pragma unroll
        for (int p = 0; p < 2; ++p)
            #pragma unroll
            for (int nb = 0; nb < 4; ++nb) acck[p][nb] += kreg[p][nb];
        f_eval(0.5f * DT_F);
        #pragma unroll
        for (int p = 0; p < 2; ++p)
            #pragma unroll
            for (int nb = 0; nb < 4; ++nb) acck[p][nb] += kreg[p][nb] * 2.0f;
        f_eval(0.5f * DT_F);
        #pragma unroll
        for (int p = 0; p < 2; ++p)
            #pragma unroll
            for (int nb = 0; nb < 4; ++nb) acck[p][nb] += kreg[p][nb] * 2.0f;
        f_eval(DT_F);
        #pragma unroll
        for (int p = 0; p < 2; ++p)
            #pragma unroll
            for (int nb = 0; nb < 4; ++nb) {
                acck[p][nb] += kreg[p][nb];
                xreg[p][nb] += acck[p][nb] * (DT_F / 6.0f);
            }

        if (s >= 10 && (s & 1)) {
            // regularization eval at post-step states 12,14,16,18,20
            f_eval(0.0f);   // kreg = f(x); harmless before next step's k1 (c=0)
            float amax[4] = {0,0,0,0};
            #pragma unroll
            for (int nb = 0; nb < 4; ++nb)
                #pragma unroll
                for (int p = 0; p < 2; ++p)
                    #pragma unroll
                    for (int r = 0; r < 4; ++r)
                        amax[nb] = fmaxf(amax[nb], fabsf(kreg[p][nb][r]));
            #pragma unroll
            for (int nb = 0; nb < 4; ++nb) {
                amax[nb] = fmaxf(amax[nb], __shfl_xor(amax[nb], 16));
                amax[nb] = fmaxf(amax[nb], __shfl_xor(amax[nb], 32));
            }
            if (lane < 16) {
                #pragma unroll
                for (int nb = 0; nb < 4; ++nb) rmx[(w * 4 + nb) * 16 + l15] = amax[nb];
            }
            __syncthreads();
            float rmax_[4];
            #pragma unroll
            for (int nb = 0; nb < 4; ++nb) {
                float m = rmx[(0 * 4 + nb) * 16 + l15];
                m = fmaxf(m, rmx[(1 * 4 + nb) * 16 + l15]);
                m = fmaxf(m, rmx[(2 * 4 + nb) * 16 + l15]);
                m = fmaxf(m, rmx[(3 * 4 + nb) * 16 + l15]);
                rmax_[nb] = m;
            }
            float se[4] = {0,0,0,0}, sa[4] = {0,0,0,0};
            #pragma unroll
            for (int nb = 0; nb < 4; ++nb)
                #pragma unroll
                for (int p = 0; p < 2; ++p)
                    #pragma unroll
                    for (int r = 0; r < 4; ++r) {
                        float a = fabsf(kreg[p][nb][r]);
                        float e = __expf(a - rmax_[nb]);
                        se[nb] += e; sa[nb] = fmaf(a, e, sa[nb]);
                    }
            #pragma unroll
            for (int nb = 0; nb < 4; ++nb) {
                se[nb] += __shfl_xor(se[nb], 16); se[nb] += __shfl_xor(se[nb], 32);
                sa[nb] += __shfl_xor(sa[nb], 16); sa[nb] += __shfl_xor(sa[nb], 32);
            }
            __syncthreads();   // rmx reads done before lnb overwrite (shared region safety)
            if (lane < 16) {
                #pragma unroll
                for (int nb = 0; nb < 4; ++nb) {
                    lnb[((w * 4 + nb) * 16 + l15) * 2 + 0] = se[nb];
                    lnb[((w * 4 + nb) * 16 + l15) * 2 + 1] = sa[nb];
                }
            }
            __syncthreads();
            if (w == 0) {
                // lane covers row (16*(lane>>4) + l15)
                float nse = 0.f, nsa = 0.f;
                #pragma unroll
                for (int ww = 0; ww < 4; ++ww) {
                    nse += lnb[((ww * 4 + g) * 16 + l15) * 2 + 0];
                    nsa += lnb[((ww * 4 + g) * 16 + l15) * 2 + 1];
                }
                float nrm = nsa / nse;
                #pragma unroll
                for (int m = 1; m < 64; m <<= 1) nrm += __shfl_xor(nrm, m);
                if (lane == 0) regtot += nrm;
            }
            __syncthreads();
        }
    }

    #pragma unroll
    for (int p = 0; p < 2; ++p)
        #pragma unroll
        for (int nb = 0; nb < 4; ++nb) {
            int brow = row0 + 16 * nb + l15;
            int ucol = 16 * (2 * w + p) + 4 * g;
            *(f32x4*)&out[brow * 128 + ucol] = xreg[p][nb];
        }
    if (t == 0) regPart[blockIdx.x] = regtot;
}

__global__ __launch_bounds__(64)
void finalize_reg(const float* __restrict__ regPart, float* __restrict__ outReg)
{
    int t = threadIdx.x;
    float s = regPart[t] + regPart[t + 64] + regPart[t + 128] + regPart[t + 192];
    #pragma unroll
    for (int m = 1; m < 64; m <<= 1) s += __shfl_xor(s, m);
    if (t == 0) outReg[0] = s * (1.0f / (5.0f * 16384.0f));
}

extern "C" void kernel_launch(void* const* d_in, const int* in_sizes, int n_in,
                              void* d_out, int out_size, void* d_ws, size_t ws_size,
                              hipStream_t stream)
{
    (void)in_sizes; (void)n_in; (void)out_size; (void)ws_size;
    const float* x0    = (const float*)d_in[0];
    const float* W1    = (const float*)d_in[1];
    const float* b1    = (const float*)d_in[2];
    const float* gamma = (const float*)d_in[3];
    const float* beta  = (const float*)d_in[4];
    const float* W2    = (const float*)d_in[5];
    const float* b2    = (const float*)d_in[6];
    float* out = (float*)d_out;

    ushort_t* w1p = (ushort_t*)d_ws;                       // 256 KB
    ushort_t* w2p = w1p + 131072;                          // 256 KB
    float* regPart = (float*)((char*)d_ws + 524288);       // 1 KB

    pack_weights<<<64, 256, 0, stream>>>(W1, W2, w1p, w2p);
    node_ode<<<256, 256, 108032, stream>>>(x0, gamma, beta, b1, b2, w1p, w2p, out, regPart);
    finalize_reg<<<1, 64, 0, stream>>>(regPart, out + 2097152);
}

// Round 3
// 856.181 us; speedup vs baseline: 8.3811x; 2.8617x over previous
//
#include <hip/hip_runtime.h>
#include <hip/hip_bf16.h>

typedef short bf16x8 __attribute__((ext_vector_type(8)));
typedef float f32x4  __attribute__((ext_vector_type(4)));
typedef unsigned short ushort_t;

#define DT_F     0.1f
#define LN_EPS_F 1e-3f

__device__ __forceinline__ ushort_t f2bf(float v) {
    union { float f; unsigned u; } x; x.f = v;
    unsigned r = x.u + 0x7fffu + ((x.u >> 16) & 1u);   // round-to-nearest-even
    return (ushort_t)(r >> 16);
}
__device__ __forceinline__ float bf2f(ushort_t h) {
    union { unsigned u; float f; } y; y.u = ((unsigned)h) << 16;
    return y.f;
}

// ---------------------------------------------------------------------------
// Pack W1 (128x512) and W2 (512x128) into MFMA A-fragment order (swapped GEMM:
// A = W^T), single bf16 (hi only), k-permutation pi(ks,g,j)=16*(2ks+(j>>2))+4g+(j&3).
// W1pack: [mh 32][ku 4][lane 64][8]   W2pack: [mu2 8][kh 16][lane 64][8]
// ---------------------------------------------------------------------------
__global__ __launch_bounds__(256)
void pack_weights(const float* __restrict__ W1, const float* __restrict__ W2,
                  ushort_t* __restrict__ w1p, ushort_t* __restrict__ w2p)
{
    int tid  = blockIdx.x * 256 + threadIdx.x;   // 0..16383
    int lane = tid & 63;
    int g = lane >> 4, l15 = lane & 15;
    int fi = tid >> 6;                            // 0..255
    bf16x8 hi;
    if (fi < 128) {
        int mh = fi >> 2, ku = fi & 3;
        #pragma unroll
        for (int j = 0; j < 8; ++j) {
            int u = 16 * (2 * ku + (j >> 2)) + 4 * g + (j & 3);
            hi[j] = (short)f2bf(W1[u * 512 + 16 * mh + l15]);
        }
        ((bf16x8*)w1p)[fi * 64 + lane] = hi;
    } else {
        int fj = fi - 128;
        int mu2 = fj >> 4, kh = fj & 15;
        #pragma unroll
        for (int j = 0; j < 8; ++j) {
            int hr = 16 * (2 * kh + (j >> 2)) + 4 * g + (j & 3);
            hi[j] = (short)f2bf(W2[hr * 128 + 16 * mu2 + l15]);
        }
        ((bf16x8*)w2p)[fj * 64 + lane] = hi;
    }
}

// ---------------------------------------------------------------------------
// Persistent ODE kernel: 256 blocks x 512 threads (8 waves); block owns 64 rows.
// Wave w: mm1 computes h-cols 16*(4w)..16*(4w+3)+15 ; mm2 computes u-cols 16w..16w+15.
// ---------------------------------------------------------------------------
__global__ __launch_bounds__(512, 2)
void node_ode(const float* __restrict__ x0,
              const float* __restrict__ gamma, const float* __restrict__ beta,
              const float* __restrict__ b1,    const float* __restrict__ b2,
              const ushort_t* __restrict__ w1p, const ushort_t* __restrict__ w2p,
              float* __restrict__ out, float* __restrict__ regPart)
{
    extern __shared__ char smem[];
    ushort_t* xinh = (ushort_t*)smem;              // [4nb][4ku][64][8]  16 KB
    ushort_t* xinl = (ushort_t*)(smem + 16384);    // 16 KB
    ushort_t* hbuf = (ushort_t*)(smem + 32768);    // [16kh][4nb][64][8] 64 KB
    float*    gbuf = (float*)(smem + 98304);       // [512][{gamma,beta}] 4 KB
    float*    b1b  = (float*)(smem + 102400);      // 2 KB
    float*    b2b  = (float*)(smem + 104448);      // 512 B
    float*    lnb  = (float*)(smem + 104960);      // [8w][4nb][16][2] 4 KB
    float*    rmx  = (float*)(smem + 109056);      // [8w][4nb][16] 2 KB
    // total 111104 B

    const int t = threadIdx.x, lane = t & 63, w = t >> 6;
    const int g = lane >> 4, l15 = lane & 15;
    const int row0 = blockIdx.x * 64;

    const bf16x8* w1v = (const bf16x8*)w1p;
    const bf16x8* w2v = (const bf16x8*)w2p;

    for (int c = t; c < 512; c += 512) {
        gbuf[2 * c] = gamma[c]; gbuf[2 * c + 1] = beta[c]; b1b[c] = b1[c];
    }
    if (t < 128) b2b[t] = b2[t];

    // x state: xreg[nb] = rows 16nb+l15, ucols 16w+4g..+3
    f32x4 xreg[4], acck[4], kreg[4];
    #pragma unroll
    for (int nb = 0; nb < 4; ++nb) {
        int brow = row0 + 16 * nb + l15;
        int ucol = 16 * w + 4 * g;
        xreg[nb] = *(const f32x4*)&x0[brow * 128 + ucol];
        kreg[nb] = (f32x4)0.0f;
    }
    __syncthreads();

    float regtot = 0.0f;

    auto build_xin = [&](float c) {
        #pragma unroll
        for (int nb = 0; nb < 4; ++nb) {
            f32x4 xv = xreg[nb];
            if (c != 0.0f) xv += kreg[nb] * c;
            ushort_t h0 = f2bf(xv[0]), h1 = f2bf(xv[1]), h2 = f2bf(xv[2]), h3 = f2bf(xv[3]);
            ushort_t q0 = f2bf(xv[0] - bf2f(h0)), q1 = f2bf(xv[1] - bf2f(h1));
            ushort_t q2 = f2bf(xv[2] - bf2f(h2)), q3 = f2bf(xv[3] - bf2f(h3));
            unsigned h01 = (unsigned)h0 | ((unsigned)h1 << 16);
            unsigned h23 = (unsigned)h2 | ((unsigned)h3 << 16);
            unsigned l01 = (unsigned)q0 | ((unsigned)q1 << 16);
            unsigned l23 = (unsigned)q2 | ((unsigned)q3 << 16);
            int off = ((nb * 4 + (w >> 1)) * 64 + lane) * 8 + (w & 1) * 4;
            *reinterpret_cast<uint2*>(&xinh[off]) = make_uint2(h01, h23);
            *reinterpret_cast<uint2*>(&xinl[off]) = make_uint2(l01, l23);
        }
    };

    // mm1 (C1^T = W1^T x^T) + LayerNorm + ReLU -> hbuf (bf16)
    auto do_mm1_ln = [&]() {
        f32x4 acc[4][4];
        #pragma unroll
        for (int mhi = 0; mhi < 4; ++mhi) {
            int mh = 4 * w + mhi;
            f32x4 bv = *(const f32x4*)&b1b[16 * mh + 4 * g];
            #pragma unroll
            for (int nb = 0; nb < 4; ++nb) acc[mhi][nb] = bv;
        }
        #pragma unroll
        for (int ku = 0; ku < 4; ++ku) {
            bf16x8 Bh[4], Bl[4];
            #pragma unroll
            for (int nb = 0; nb < 4; ++nb) {
                int off = ((nb * 4 + ku) * 64 + lane) * 8;
                Bh[nb] = *(const bf16x8*)&xinh[off];
                Bl[nb] = *(const bf16x8*)&xinl[off];
            }
            #pragma unroll
            for (int mhi = 0; mhi < 4; ++mhi) {
                bf16x8 Ah = w1v[((4 * w + mhi) * 4 + ku) * 64 + lane];
                #pragma unroll
                for (int nb = 0; nb < 4; ++nb)
                    acc[mhi][nb] = __builtin_amdgcn_mfma_f32_16x16x32_bf16(Ah, Bh[nb], acc[mhi][nb], 0, 0, 0);
                #pragma unroll
                for (int nb = 0; nb < 4; ++nb)
                    acc[mhi][nb] = __builtin_amdgcn_mfma_f32_16x16x32_bf16(Ah, Bl[nb], acc[mhi][nb], 0, 0, 0);
            }
        }
        // LayerNorm stats: this wave holds 64 of 512 cols for rows 16nb+l15
        float s1[4] = {0,0,0,0}, s2[4] = {0,0,0,0};
        #pragma unroll
        for (int nb = 0; nb < 4; ++nb)
            #pragma unroll
            for (int mhi = 0; mhi < 4; ++mhi)
                #pragma unroll
                for (int r = 0; r < 4; ++r) {
                    float v = acc[mhi][nb][r];
                    s1[nb] += v; s2[nb] = fmaf(v, v, s2[nb]);
                }
        #pragma unroll
        for (int nb = 0; nb < 4; ++nb) {
            s1[nb] += __shfl_xor(s1[nb], 16); s1[nb] += __shfl_xor(s1[nb], 32);
            s2[nb] += __shfl_xor(s2[nb], 16); s2[nb] += __shfl_xor(s2[nb], 32);
        }
        if (lane < 16) {
            #pragma unroll
            for (int nb = 0; nb < 4; ++nb) {
                lnb[((w * 4 + nb) * 16 + l15) * 2 + 0] = s1[nb];
                lnb[((w * 4 + nb) * 16 + l15) * 2 + 1] = s2[nb];
            }
        }
        __syncthreads();
        float mu_[4], rs_[4];
        #pragma unroll
        for (int nb = 0; nb < 4; ++nb) {
            float t1 = 0.f, t2 = 0.f;
            #pragma unroll
            for (int ww = 0; ww < 8; ++ww) {
                t1 += lnb[((ww * 4 + nb) * 16 + l15) * 2 + 0];
                t2 += lnb[((ww * 4 + nb) * 16 + l15) * 2 + 1];
            }
            float m = t1 * (1.0f / 512.0f);
            float var = t2 * (1.0f / 512.0f) - m * m;
            mu_[nb] = m; rs_[nb] = rsqrtf(var + LN_EPS_F);
        }
        // apply LN * gamma + beta, ReLU, bf16 -> hbuf
        #pragma unroll
        for (int mhi = 0; mhi < 4; ++mhi) {
            int mh = 4 * w + mhi;
            float2 gp[4];
            #pragma unroll
            for (int r = 0; r < 4; ++r) gp[r] = *(const float2*)&gbuf[(16 * mh + 4 * g + r) * 2];
            #pragma unroll
            for (int nb = 0; nb < 4; ++nb) {
                float v0 = fmaxf(fmaf((acc[mhi][nb][0] - mu_[nb]) * rs_[nb], gp[0].x, gp[0].y), 0.f);
                float v1 = fmaxf(fmaf((acc[mhi][nb][1] - mu_[nb]) * rs_[nb], gp[1].x, gp[1].y), 0.f);
                float v2 = fmaxf(fmaf((acc[mhi][nb][2] - mu_[nb]) * rs_[nb], gp[2].x, gp[2].y), 0.f);
                float v3 = fmaxf(fmaf((acc[mhi][nb][3] - mu_[nb]) * rs_[nb], gp[3].x, gp[3].y), 0.f);
                unsigned q01 = (unsigned)f2bf(v0) | ((unsigned)f2bf(v1) << 16);
                unsigned q23 = (unsigned)f2bf(v2) | ((unsigned)f2bf(v3) << 16);
                int off = (((mh >> 1) * 4 + nb) * 64 + lane) * 8 + (mh & 1) * 4;
                *reinterpret_cast<uint2*>(&hbuf[off]) = make_uint2(q01, q23);
            }
        }
    };

    // mm2 (out^T = W2^T h^T) -> kreg ; wave w owns mu2 = w
    auto do_mm2 = [&]() {
        f32x4 bv = *(const f32x4*)&b2b[16 * w + 4 * g];
        #pragma unroll
        for (int nb = 0; nb < 4; ++nb) kreg[nb] = bv;
        #pragma unroll
        for (int kh = 0; kh < 16; ++kh) {
            bf16x8 Bf[4];
            #pragma unroll
            for (int nb = 0; nb < 4; ++nb)
                Bf[nb] = *(const bf16x8*)&hbuf[((kh * 4 + nb) * 64 + lane) * 8];
            bf16x8 Ah = w2v[(w * 16 + kh) * 64 + lane];
            #pragma unroll
            for (int nb = 0; nb < 4; ++nb)
                kreg[nb] = __builtin_amdgcn_mfma_f32_16x16x32_bf16(Ah, Bf[nb], kreg[nb], 0, 0, 0);
        }
    };

    auto f_eval = [&](float c) {
        build_xin(c);
        __syncthreads();
        do_mm1_ln();
        __syncthreads();
        do_mm2();
    };

    for (int s = 0; s < 20; ++s) {
        #pragma unroll
        for (int nb = 0; nb < 4; ++nb) acck[nb] = (f32x4)0.0f;

        f_eval(0.0f);
        #pragma unroll
        for (int nb = 0; nb < 4; ++nb) acck[nb] += kreg[nb];
        f_eval(0.5f * DT_F);
        #pragma unroll
        for (int nb = 0; nb < 4; ++nb) acck[nb] += kreg[nb] * 2.0f;
        f_eval(0.5f * DT_F);
        #pragma unroll
        for (int nb = 0; nb < 4; ++nb) acck[nb] += kreg[nb] * 2.0f;
        f_eval(DT_F);
        #pragma unroll
        for (int nb = 0; nb < 4; ++nb) {
            acck[nb] += kreg[nb];
            xreg[nb] += acck[nb] * (DT_F / 6.0f);
        }

        if (s >= 10 && (s & 1)) {
            // regularization eval at post-step states 12,14,16,18,20
            f_eval(0.0f);
            float amax[4] = {0,0,0,0};
            #pragma unroll
            for (int nb = 0; nb < 4; ++nb)
                #pragma unroll
                for (int r = 0; r < 4; ++r)
                    amax[nb] = fmaxf(amax[nb], fabsf(kreg[nb][r]));
            #pragma unroll
            for (int nb = 0; nb < 4; ++nb) {
                amax[nb] = fmaxf(amax[nb], __shfl_xor(amax[nb], 16));
                amax[nb] = fmaxf(amax[nb], __shfl_xor(amax[nb], 32));
            }
            if (lane < 16) {
                #pragma unroll
                for (int nb = 0; nb < 4; ++nb) rmx[(w * 4 + nb) * 16 + l15] = amax[nb];
            }
            __syncthreads();
            float rmax_[4];
            #pragma unroll
            for (int nb = 0; nb < 4; ++nb) {
                float m = rmx[(0 * 4 + nb) * 16 + l15];
                #pragma unroll
                for (int ww = 1; ww < 8; ++ww) m = fmaxf(m, rmx[(ww * 4 + nb) * 16 + l15]);
                rmax_[nb] = m;
            }
            float se[4] = {0,0,0,0}, sa[4] = {0,0,0,0};
            #pragma unroll
            for (int nb = 0; nb < 4; ++nb)
                #pragma unroll
                for (int r = 0; r < 4; ++r) {
                    float a = fabsf(kreg[nb][r]);
                    float e = __expf(a - rmax_[nb]);
                    se[nb] += e; sa[nb] = fmaf(a, e, sa[nb]);
                }
            #pragma unroll
            for (int nb = 0; nb < 4; ++nb) {
                se[nb] += __shfl_xor(se[nb], 16); se[nb] += __shfl_xor(se[nb], 32);
                sa[nb] += __shfl_xor(sa[nb], 16); sa[nb] += __shfl_xor(sa[nb], 32);
            }
            if (lane < 16) {
                #pragma unroll
                for (int nb = 0; nb < 4; ++nb) {
                    lnb[((w * 4 + nb) * 16 + l15) * 2 + 0] = se[nb];
                    lnb[((w * 4 + nb) * 16 + l15) * 2 + 1] = sa[nb];
                }
            }
            __syncthreads();
            if (w == 0) {
                // lane covers row 16*g + l15 (nb = g)
                float nse = 0.f, nsa = 0.f;
                #pragma unroll
                for (int ww = 0; ww < 8; ++ww) {
                    nse += lnb[((ww * 4 + g) * 16 + l15) * 2 + 0];
                    nsa += lnb[((ww * 4 + g) * 16 + l15) * 2 + 1];
                }
                float nrm = nsa / nse;
                #pragma unroll
                for (int m = 1; m < 64; m <<= 1) nrm += __shfl_xor(nrm, m);
                if (lane == 0) regtot += nrm;
            }
            __syncthreads();
        }
    }

    #pragma unroll
    for (int nb = 0; nb < 4; ++nb) {
        int brow = row0 + 16 * nb + l15;
        int ucol = 16 * w + 4 * g;
        *(f32x4*)&out[brow * 128 + ucol] = xreg[nb];
    }
    if (t == 0) regPart[blockIdx.x] = regtot;
}

__global__ __launch_bounds__(64)
void finalize_reg(const float* __restrict__ regPart, float* __restrict__ outReg)
{
    int t = threadIdx.x;
    float s = regPart[t] + regPart[t + 64] + regPart[t + 128] + regPart[t + 192];
    #pragma unroll
    for (int m = 1; m < 64; m <<= 1) s += __shfl_xor(s, m);
    if (t == 0) outReg[0] = s * (1.0f / (5.0f * 16384.0f));
}

extern "C" void kernel_launch(void* const* d_in, const int* in_sizes, int n_in,
                              void* d_out, int out_size, void* d_ws, size_t ws_size,
                              hipStream_t stream)
{
    (void)in_sizes; (void)n_in; (void)out_size; (void)ws_size;
    const float* x0    = (const float*)d_in[0];
    const float* W1    = (const float*)d_in[1];
    const float* b1    = (const float*)d_in[2];
    const float* gamma = (const float*)d_in[3];
    const float* beta  = (const float*)d_in[4];
    const float* W2    = (const float*)d_in[5];
    const float* b2    = (const float*)d_in[6];
    float* out = (float*)d_out;

    ushort_t* w1p = (ushort_t*)d_ws;                       // 128 KB
    ushort_t* w2p = w1p + 65536;                           // 128 KB
    float* regPart = (float*)((char*)d_ws + 262144);       // 1 KB

    pack_weights<<<64, 256, 0, stream>>>(W1, W2, w1p, w2p);
    node_ode<<<256, 512, 111104, stream>>>(x0, gamma, beta, b1, b2, w1p, w2p, out, regPart);
    finalize_reg<<<1, 64, 0, stream>>>(regPart, out + 2097152);
}

// Round 4
// 720.393 us; speedup vs baseline: 9.9608x; 1.1885x over previous
//
#include <hip/hip_runtime.h>
#include <hip/hip_bf16.h>

typedef short bf16x8 __attribute__((ext_vector_type(8)));
typedef float f32x4  __attribute__((ext_vector_type(4)));
typedef unsigned short ushort_t;

#define DT_F     0.1f
#define LN_EPS_F 1e-3f

__device__ __forceinline__ ushort_t f2bf(float v) {
    union { float f; unsigned u; } x; x.f = v;
    unsigned r = x.u + 0x7fffu + ((x.u >> 16) & 1u);   // round-to-nearest-even
    return (ushort_t)(r >> 16);
}
__device__ __forceinline__ unsigned pk2(float a, float b) {
    return (unsigned)f2bf(a) | ((unsigned)f2bf(b) << 16);
}

// ---------------------------------------------------------------------------
// Pack W1 (128x512) and W2 (512x128) into MFMA A-fragment order (swapped GEMM:
// A = W^T), single bf16, k-permutation pi(ks,g,j)=16*(2ks+(j>>2))+4g+(j&3).
// W1pack: [mh 32][ku 4][lane 64][8]   W2pack: [mu2 8][kh 16][lane 64][8]
// ---------------------------------------------------------------------------
__global__ __launch_bounds__(256)
void pack_weights(const float* __restrict__ W1, const float* __restrict__ W2,
                  ushort_t* __restrict__ w1p, ushort_t* __restrict__ w2p)
{
    int tid  = blockIdx.x * 256 + threadIdx.x;   // 0..16383
    int lane = tid & 63;
    int g = lane >> 4, l15 = lane & 15;
    int fi = tid >> 6;                            // 0..255
    bf16x8 hi;
    if (fi < 128) {
        int mh = fi >> 2, ku = fi & 3;
        #pragma unroll
        for (int j = 0; j < 8; ++j) {
            int u = 16 * (2 * ku + (j >> 2)) + 4 * g + (j & 3);
            hi[j] = (short)f2bf(W1[u * 512 + 16 * mh + l15]);
        }
        ((bf16x8*)w1p)[fi * 64 + lane] = hi;
    } else {
        int fj = fi - 128;
        int mu2 = fj >> 4, kh = fj & 15;
        #pragma unroll
        for (int j = 0; j < 8; ++j) {
            int hr = 16 * (2 * kh + (j >> 2)) + 4 * g + (j & 3);
            hi[j] = (short)f2bf(W2[hr * 128 + 16 * mu2 + l15]);
        }
        ((bf16x8*)w2p)[fj * 64 + lane] = hi;
    }
}

// ---------------------------------------------------------------------------
// Persistent ODE kernel: 256 blocks x 512 threads (8 waves); block owns 64 rows.
// Wave w: mm1 computes h-cols 16*(4w)..16*(4w+3)+15 ; mm2 computes u-cols 16w..16w+15.
// W2 fragments pinned in VGPRs for the whole kernel.
// ---------------------------------------------------------------------------
__global__ __launch_bounds__(512, 1)
void node_ode(const float* __restrict__ x0,
              const float* __restrict__ gamma, const float* __restrict__ beta,
              const float* __restrict__ b1,    const float* __restrict__ b2,
              const ushort_t* __restrict__ w1p, const ushort_t* __restrict__ w2p,
              float* __restrict__ out, float* __restrict__ regPart)
{
    extern __shared__ char smem[];
    ushort_t* xinh = (ushort_t*)smem;              // [4nb][4ku][2half][64][4]  16 KB
    ushort_t* hbuf = (ushort_t*)(smem + 16384);    // [16kh][4nb][64][8]        64 KB
    float*    gbuf = (float*)(smem + 81920);       // [512][{gamma,beta}]        4 KB
    float*    b1b  = (float*)(smem + 86016);       // 2 KB
    float*    b2b  = (float*)(smem + 88064);       // 512 B
    float*    lnb  = (float*)(smem + 88576);       // [8w][4nb][16][2]           4 KB
    float*    rmx  = (float*)(smem + 92672);       // [8w][4nb][16]              2 KB
    // total 94720 B

    const int t = threadIdx.x, lane = t & 63, w = t >> 6;
    const int g = lane >> 4, l15 = lane & 15;
    const int row0 = blockIdx.x * 64;

    const bf16x8* w1v = (const bf16x8*)w1p;
    const bf16x8* w2v = (const bf16x8*)w2p;

    if (t < 512) {
        gbuf[2 * t] = gamma[t]; gbuf[2 * t + 1] = beta[t]; b1b[t] = b1[t];
    }
    if (t < 128) b2b[t] = b2[t];

    // Pin W2 fragments (wave w owns mu2 = w): 16 frags = 64 VGPRs, loaded once.
    bf16x8 W2r[16];
    #pragma unroll
    for (int kh = 0; kh < 16; ++kh)
        W2r[kh] = w2v[(w * 16 + kh) * 64 + lane];

    // x state: xreg[nb] = rows 16nb+l15, ucols 16w+4g..+3
    f32x4 xreg[4], acck[4], kreg[4];
    #pragma unroll
    for (int nb = 0; nb < 4; ++nb) {
        int brow = row0 + 16 * nb + l15;
        int ucol = 16 * w + 4 * g;
        xreg[nb] = *(const f32x4*)&x0[brow * 128 + ucol];
        kreg[nb] = (f32x4)0.0f;
    }
    __syncthreads();

    float regtot = 0.0f;

    // xin write slot: ku = w>>1, half = w&1; contiguous 8B per lane (no bank conflict)
    auto build_xin = [&](float c) {
        #pragma unroll
        for (int nb = 0; nb < 4; ++nb) {
            f32x4 xv = xreg[nb];
            if (c != 0.0f) xv += kreg[nb] * c;
            unsigned h01 = pk2(xv[0], xv[1]);
            unsigned h23 = pk2(xv[2], xv[3]);
            int off = (((nb * 4 + (w >> 1)) * 2 + (w & 1)) * 64 + lane) * 4;
            *reinterpret_cast<uint2*>(&xinh[off]) = make_uint2(h01, h23);
        }
    };

    // mm1 (C1^T = W1^T x^T) + LayerNorm + ReLU -> hbuf (bf16)
    auto do_mm1_ln = [&]() {
        f32x4 acc[4][4];
        #pragma unroll
        for (int mhi = 0; mhi < 4; ++mhi) {
            int mh = 4 * w + mhi;
            f32x4 bv = *(const f32x4*)&b1b[16 * mh + 4 * g];
            #pragma unroll
            for (int nb = 0; nb < 4; ++nb) acc[mhi][nb] = bv;
        }
        #pragma unroll
        for (int ku = 0; ku < 4; ++ku) {
            bf16x8 Bh[4];
            #pragma unroll
            for (int nb = 0; nb < 4; ++nb) {
                int base = (((nb * 4 + ku) * 2) * 64 + lane) * 4;
                union { uint2 u2[2]; bf16x8 v; } uu;
                uu.u2[0] = *reinterpret_cast<const uint2*>(&xinh[base]);        // half 0
                uu.u2[1] = *reinterpret_cast<const uint2*>(&xinh[base + 256]);  // half 1
                Bh[nb] = uu.v;
            }
            #pragma unroll
            for (int mhi = 0; mhi < 4; ++mhi) {
                bf16x8 Ah = w1v[((4 * w + mhi) * 4 + ku) * 64 + lane];
                #pragma unroll
                for (int nb = 0; nb < 4; ++nb)
                    acc[mhi][nb] = __builtin_amdgcn_mfma_f32_16x16x32_bf16(Ah, Bh[nb], acc[mhi][nb], 0, 0, 0);
            }
        }
        // LayerNorm stats: this wave holds 64 of 512 cols for rows 16nb+l15
        float s1[4] = {0,0,0,0}, s2[4] = {0,0,0,0};
        #pragma unroll
        for (int nb = 0; nb < 4; ++nb)
            #pragma unroll
            for (int mhi = 0; mhi < 4; ++mhi)
                #pragma unroll
                for (int r = 0; r < 4; ++r) {
                    float v = acc[mhi][nb][r];
                    s1[nb] += v; s2[nb] = fmaf(v, v, s2[nb]);
                }
        #pragma unroll
        for (int nb = 0; nb < 4; ++nb) {
            s1[nb] += __shfl_xor(s1[nb], 16); s1[nb] += __shfl_xor(s1[nb], 32);
            s2[nb] += __shfl_xor(s2[nb], 16); s2[nb] += __shfl_xor(s2[nb], 32);
        }
        if (lane < 16) {
            #pragma unroll
            for (int nb = 0; nb < 4; ++nb) {
                lnb[((w * 4 + nb) * 16 + l15) * 2 + 0] = s1[nb];
                lnb[((w * 4 + nb) * 16 + l15) * 2 + 1] = s2[nb];
            }
        }
        __syncthreads();
        float mu_[4], rs_[4];
        #pragma unroll
        for (int nb = 0; nb < 4; ++nb) {
            float t1 = 0.f, t2 = 0.f;
            #pragma unroll
            for (int ww = 0; ww < 8; ++ww) {
                t1 += lnb[((ww * 4 + nb) * 16 + l15) * 2 + 0];
                t2 += lnb[((ww * 4 + nb) * 16 + l15) * 2 + 1];
            }
            float m = t1 * (1.0f / 512.0f);
            float var = t2 * (1.0f / 512.0f) - m * m;
            mu_[nb] = m; rs_[nb] = rsqrtf(var + LN_EPS_F);
        }
        // apply LN * gamma + beta, ReLU, bf16 -> hbuf; one b128 write per (kh,nb)
        #pragma unroll
        for (int khl = 0; khl < 2; ++khl) {
            float2 gp[2][4];
            #pragma unroll
            for (int half = 0; half < 2; ++half) {
                int mh = 4 * w + 2 * khl + half;
                #pragma unroll
                for (int r = 0; r < 4; ++r)
                    gp[half][r] = *(const float2*)&gbuf[(16 * mh + 4 * g + r) * 2];
            }
            #pragma unroll
            for (int nb = 0; nb < 4; ++nb) {
                float v[8];
                #pragma unroll
                for (int half = 0; half < 2; ++half) {
                    int mhi = 2 * khl + half;
                    #pragma unroll
                    for (int r = 0; r < 4; ++r)
                        v[half * 4 + r] = fmaxf(fmaf((acc[mhi][nb][r] - mu_[nb]) * rs_[nb],
                                                     gp[half][r].x, gp[half][r].y), 0.f);
                }
                uint4 q;
                q.x = pk2(v[0], v[1]); q.y = pk2(v[2], v[3]);
                q.z = pk2(v[4], v[5]); q.w = pk2(v[6], v[7]);
                int kh = 2 * w + khl;
                *reinterpret_cast<uint4*>(&hbuf[((kh * 4 + nb) * 64 + lane) * 8]) = q;
            }
        }
    };

    // mm2 (out^T = W2^T h^T) -> kreg ; W2 frags pinned in regs
    auto do_mm2 = [&]() {
        f32x4 bv = *(const f32x4*)&b2b[16 * w + 4 * g];
        #pragma unroll
        for (int nb = 0; nb < 4; ++nb) kreg[nb] = bv;
        #pragma unroll
        for (int kh = 0; kh < 16; ++kh) {
            bf16x8 Bf[4];
            #pragma unroll
            for (int nb = 0; nb < 4; ++nb)
                Bf[nb] = *(const bf16x8*)&hbuf[((kh * 4 + nb) * 64 + lane) * 8];
            #pragma unroll
            for (int nb = 0; nb < 4; ++nb)
                kreg[nb] = __builtin_amdgcn_mfma_f32_16x16x32_bf16(W2r[kh], Bf[nb], kreg[nb], 0, 0, 0);
        }
    };

    auto f_eval = [&](float c) {
        build_xin(c);
        __syncthreads();
        do_mm1_ln();
        __syncthreads();
        do_mm2();
    };

    for (int s = 0; s < 20; ++s) {
        #pragma unroll
        for (int nb = 0; nb < 4; ++nb) acck[nb] = (f32x4)0.0f;

        f_eval(0.0f);
        #pragma unroll
        for (int nb = 0; nb < 4; ++nb) acck[nb] += kreg[nb];
        f_eval(0.5f * DT_F);
        #pragma unroll
        for (int nb = 0; nb < 4; ++nb) acck[nb] += kreg[nb] * 2.0f;
        f_eval(0.5f * DT_F);
        #pragma unroll
        for (int nb = 0; nb < 4; ++nb) acck[nb] += kreg[nb] * 2.0f;
        f_eval(DT_F);
        #pragma unroll
        for (int nb = 0; nb < 4; ++nb) {
            acck[nb] += kreg[nb];
            xreg[nb] += acck[nb] * (DT_F / 6.0f);
        }

        if (s >= 10 && (s & 1)) {
            // regularization eval at post-step states 12,14,16,18,20
            f_eval(0.0f);
            float amax[4] = {0,0,0,0};
            #pragma unroll
            for (int nb = 0; nb < 4; ++nb)
                #pragma unroll
                for (int r = 0; r < 4; ++r)
                    amax[nb] = fmaxf(amax[nb], fabsf(kreg[nb][r]));
            #pragma unroll
            for (int nb = 0; nb < 4; ++nb) {
                amax[nb] = fmaxf(amax[nb], __shfl_xor(amax[nb], 16));
                amax[nb] = fmaxf(amax[nb], __shfl_xor(amax[nb], 32));
            }
            if (lane < 16) {
                #pragma unroll
                for (int nb = 0; nb < 4; ++nb) rmx[(w * 4 + nb) * 16 + l15] = amax[nb];
            }
            __syncthreads();
            float rmax_[4];
            #pragma unroll
            for (int nb = 0; nb < 4; ++nb) {
                float m = rmx[(0 * 4 + nb) * 16 + l15];
                #pragma unroll
                for (int ww = 1; ww < 8; ++ww) m = fmaxf(m, rmx[(ww * 4 + nb) * 16 + l15]);
                rmax_[nb] = m;
            }
            float se[4] = {0,0,0,0}, sa[4] = {0,0,0,0};
            #pragma unroll
            for (int nb = 0; nb < 4; ++nb)
                #pragma unroll
                for (int r = 0; r < 4; ++r) {
                    float a = fabsf(kreg[nb][r]);
                    float e = __expf(a - rmax_[nb]);
                    se[nb] += e; sa[nb] = fmaf(a, e, sa[nb]);
                }
            #pragma unroll
            for (int nb = 0; nb < 4; ++nb) {
                se[nb] += __shfl_xor(se[nb], 16); se[nb] += __shfl_xor(se[nb], 32);
                sa[nb] += __shfl_xor(sa[nb], 16); sa[nb] += __shfl_xor(sa[nb], 32);
            }
            if (lane < 16) {
                #pragma unroll
                for (int nb = 0; nb < 4; ++nb) {
                    lnb[((w * 4 + nb) * 16 + l15) * 2 + 0] = se[nb];
                    lnb[((w * 4 + nb) * 16 + l15) * 2 + 1] = sa[nb];
                }
            }
            __syncthreads();
            if (w == 0) {
                // lane covers row 16*g + l15 (nb = g)
                float nse = 0.f, nsa = 0.f;
                #pragma unroll
                for (int ww = 0; ww < 8; ++ww) {
                    nse += lnb[((ww * 4 + g) * 16 + l15) * 2 + 0];
                    nsa += lnb[((ww * 4 + g) * 16 + l15) * 2 + 1];
                }
                float nrm = nsa / nse;
                #pragma unroll
                for (int m = 1; m < 64; m <<= 1) nrm += __shfl_xor(nrm, m);
                if (lane == 0) regtot += nrm;
            }
            __syncthreads();
        }
    }

    #pragma unroll
    for (int nb = 0; nb < 4; ++nb) {
        int brow = row0 + 16 * nb + l15;
        int ucol = 16 * w + 4 * g;
        *(f32x4*)&out[brow * 128 + ucol] = xreg[nb];
    }
    if (t == 0) regPart[blockIdx.x] = regtot;
}

__global__ __launch_bounds__(64)
void finalize_reg(const float* __restrict__ regPart, float* __restrict__ outReg)
{
    int t = threadIdx.x;
    float s = regPart[t] + regPart[t + 64] + regPart[t + 128] + regPart[t + 192];
    #pragma unroll
    for (int m = 1; m < 64; m <<= 1) s += __shfl_xor(s, m);
    if (t == 0) outReg[0] = s * (1.0f / (5.0f * 16384.0f));
}

extern "C" void kernel_launch(void* const* d_in, const int* in_sizes, int n_in,
                              void* d_out, int out_size, void* d_ws, size_t ws_size,
                              hipStream_t stream)
{
    (void)in_sizes; (void)n_in; (void)out_size; (void)ws_size;
    const float* x0    = (const float*)d_in[0];
    const float* W1    = (const float*)d_in[1];
    const float* b1    = (const float*)d_in[2];
    const float* gamma = (const float*)d_in[3];
    const float* beta  = (const float*)d_in[4];
    const float* W2    = (const float*)d_in[5];
    const float* b2    = (const float*)d_in[6];
    float* out = (float*)d_out;

    ushort_t* w1p = (ushort_t*)d_ws;                       // 128 KB
    ushort_t* w2p = w1p + 65536;                           // 128 KB
    float* regPart = (float*)((char*)d_ws + 262144);       // 1 KB

    pack_weights<<<64, 256, 0, stream>>>(W1, W2, w1p, w2p);
    node_ode<<<256, 512, 94720, stream>>>(x0, gamma, beta, b1, b2, w1p, w2p, out, regPart);
    finalize_reg<<<1, 64, 0, stream>>>(regPart, out + 2097152);
}

// Round 5
// 534.823 us; speedup vs baseline: 13.4170x; 1.3470x over previous
//
#include <hip/hip_runtime.h>
#include <hip/hip_bf16.h>

typedef short bf16x8 __attribute__((ext_vector_type(8)));
typedef float f32x4  __attribute__((ext_vector_type(4)));
typedef unsigned short ushort_t;

#define DT_F     0.1f
#define LN_EPS_F 1e-3f

__device__ __forceinline__ ushort_t f2bf(float v) {
    union { float f; unsigned u; } x; x.f = v;
    unsigned r = x.u + 0x7fffu + ((x.u >> 16) & 1u);   // round-to-nearest-even
    return (ushort_t)(r >> 16);
}
// packed RNE f32x2 -> bf16x2 in one VALU op
__device__ __forceinline__ unsigned pk2(float a, float b) {
    unsigned r;
    asm("v_cvt_pk_bf16_f32 %0, %1, %2" : "=v"(r) : "v"(a), "v"(b));
    return r;
}

// ---------------------------------------------------------------------------
// Pack W1 (128x512) and W2 (512x128) into MFMA A-fragment order (swapped GEMM:
// A = W^T), single bf16, k-permutation pi(ks,g,j)=16*(2ks+(j>>2))+4g+(j&3).
// W1pack: [mh 32][ku 4][lane 64][8]   W2pack: [mu2 8][kh 16][lane 64][8]
// ---------------------------------------------------------------------------
__global__ __launch_bounds__(256)
void pack_weights(const float* __restrict__ W1, const float* __restrict__ W2,
                  ushort_t* __restrict__ w1p, ushort_t* __restrict__ w2p)
{
    int tid  = blockIdx.x * 256 + threadIdx.x;   // 0..16383
    int lane = tid & 63;
    int g = lane >> 4, l15 = lane & 15;
    int fi = tid >> 6;                            // 0..255
    bf16x8 hi;
    if (fi < 128) {
        int mh = fi >> 2, ku = fi & 3;
        #pragma unroll
        for (int j = 0; j < 8; ++j) {
            int u = 16 * (2 * ku + (j >> 2)) + 4 * g + (j & 3);
            hi[j] = (short)f2bf(W1[u * 512 + 16 * mh + l15]);
        }
        ((bf16x8*)w1p)[fi * 64 + lane] = hi;
    } else {
        int fj = fi - 128;
        int mu2 = fj >> 4, kh = fj & 15;
        #pragma unroll
        for (int j = 0; j < 8; ++j) {
            int hr = 16 * (2 * kh + (j >> 2)) + 4 * g + (j & 3);
            hi[j] = (short)f2bf(W2[hr * 128 + 16 * mu2 + l15]);
        }
        ((bf16x8*)w2p)[fj * 64 + lane] = hi;
    }
}

// ---------------------------------------------------------------------------
// Persistent ODE kernel: 256 blocks x 512 threads (8 waves); block owns 64 rows.
// Wave w: mm1 computes h-cols 16*(4w)..16*(4w+3)+15 ; mm2 computes u-cols 16w..16w+15.
// launch_bounds(512,2): 2 waves/EU -> VGPR cap 256 (occupancy unchanged at
// 1 block/CU) -> no scratch spills.
// ---------------------------------------------------------------------------
__global__ __launch_bounds__(512, 2)
void node_ode(const float* __restrict__ x0,
              const float* __restrict__ gamma, const float* __restrict__ beta,
              const float* __restrict__ b1,    const float* __restrict__ b2,
              const ushort_t* __restrict__ w1p, const ushort_t* __restrict__ w2p,
              float* __restrict__ out, float* __restrict__ regPart)
{
    extern __shared__ char smem[];
    ushort_t* xinh = (ushort_t*)smem;              // [4nb][4ku][2half][64][4]  16 KB
    ushort_t* hbuf = (ushort_t*)(smem + 16384);    // [16kh][4nb][64][8]        64 KB
    float*    gbuf = (float*)(smem + 81920);       // [512][{gamma,beta}]        4 KB
    float*    b1b  = (float*)(smem + 86016);       // 2 KB
    float*    b2b  = (float*)(smem + 88064);       // 512 B
    float*    lnb  = (float*)(smem + 88576);       // [8w][4nb][16][2]           4 KB
    float*    rmx  = (float*)(smem + 92672);       // [8w][4nb][16]              2 KB
    // total 94720 B

    const int t = threadIdx.x, lane = t & 63, w = t >> 6;
    const int g = lane >> 4, l15 = lane & 15;
    const int row0 = blockIdx.x * 64;

    const bf16x8* w1v = (const bf16x8*)w1p;
    const bf16x8* w2v = (const bf16x8*)w2p;

    gbuf[2 * t] = gamma[t]; gbuf[2 * t + 1] = beta[t]; b1b[t] = b1[t];
    if (t < 128) b2b[t] = b2[t];

    // x state: xreg[nb] = rows 16nb+l15, ucols 16w+4g..+3
    f32x4 xreg[4], acck[4], kreg[4];
    #pragma unroll
    for (int nb = 0; nb < 4; ++nb) {
        int brow = row0 + 16 * nb + l15;
        int ucol = 16 * w + 4 * g;
        xreg[nb] = *(const f32x4*)&x0[brow * 128 + ucol];
        kreg[nb] = (f32x4)0.0f;
    }
    __syncthreads();

    float regtot = 0.0f;

    // xin write slot: ku = w>>1, half = w&1; contiguous 8B per lane (no bank conflict)
    auto build_xin = [&](float c) {
        #pragma unroll
        for (int nb = 0; nb < 4; ++nb) {
            f32x4 xv = xreg[nb];
            if (c != 0.0f) xv += kreg[nb] * c;
            unsigned h01 = pk2(xv[0], xv[1]);
            unsigned h23 = pk2(xv[2], xv[3]);
            int off = (((nb * 4 + (w >> 1)) * 2 + (w & 1)) * 64 + lane) * 4;
            *reinterpret_cast<uint2*>(&xinh[off]) = make_uint2(h01, h23);
        }
    };

    // mm1 (C1^T = W1^T x^T) + LayerNorm + ReLU -> hbuf (bf16)
    auto do_mm1_ln = [&]() {
        f32x4 acc[4][4];
        #pragma unroll
        for (int mhi = 0; mhi < 4; ++mhi) {
            int mh = 4 * w + mhi;
            f32x4 bv = *(const f32x4*)&b1b[16 * mh + 4 * g];
            #pragma unroll
            for (int nb = 0; nb < 4; ++nb) acc[mhi][nb] = bv;
        }
        #pragma unroll
        for (int ku = 0; ku < 4; ++ku) {
            bf16x8 Bh[4];
            #pragma unroll
            for (int nb = 0; nb < 4; ++nb) {
                int base = (((nb * 4 + ku) * 2) * 64 + lane) * 4;
                union { uint2 u2[2]; bf16x8 v; } uu;
                uu.u2[0] = *reinterpret_cast<const uint2*>(&xinh[base]);        // half 0
                uu.u2[1] = *reinterpret_cast<const uint2*>(&xinh[base + 256]);  // half 1
                Bh[nb] = uu.v;
            }
            #pragma unroll
            for (int mhi = 0; mhi < 4; ++mhi) {
                bf16x8 Ah = w1v[((4 * w + mhi) * 4 + ku) * 64 + lane];
                #pragma unroll
                for (int nb = 0; nb < 4; ++nb)
                    acc[mhi][nb] = __builtin_amdgcn_mfma_f32_16x16x32_bf16(Ah, Bh[nb], acc[mhi][nb], 0, 0, 0);
            }
        }
        // LayerNorm stats: this wave holds 64 of 512 cols for rows 16nb+l15
        float s1[4] = {0,0,0,0}, s2[4] = {0,0,0,0};
        #pragma unroll
        for (int nb = 0; nb < 4; ++nb)
            #pragma unroll
            for (int mhi = 0; mhi < 4; ++mhi)
                #pragma unroll
                for (int r = 0; r < 4; ++r) {
                    float v = acc[mhi][nb][r];
                    s1[nb] += v; s2[nb] = fmaf(v, v, s2[nb]);
                }
        #pragma unroll
        for (int nb = 0; nb < 4; ++nb) {
            s1[nb] += __shfl_xor(s1[nb], 16); s1[nb] += __shfl_xor(s1[nb], 32);
            s2[nb] += __shfl_xor(s2[nb], 16); s2[nb] += __shfl_xor(s2[nb], 32);
        }
        if (lane < 16) {
            #pragma unroll
            for (int nb = 0; nb < 4; ++nb) {
                lnb[((w * 4 + nb) * 16 + l15) * 2 + 0] = s1[nb];
                lnb[((w * 4 + nb) * 16 + l15) * 2 + 1] = s2[nb];
            }
        }
        __syncthreads();
        float mu_[4], rs_[4];
        #pragma unroll
        for (int nb = 0; nb < 4; ++nb) {
            float t1 = 0.f, t2 = 0.f;
            #pragma unroll
            for (int ww = 0; ww < 8; ++ww) {
                t1 += lnb[((ww * 4 + nb) * 16 + l15) * 2 + 0];
                t2 += lnb[((ww * 4 + nb) * 16 + l15) * 2 + 1];
            }
            float m = t1 * (1.0f / 512.0f);
            float var = t2 * (1.0f / 512.0f) - m * m;
            mu_[nb] = m; rs_[nb] = rsqrtf(var + LN_EPS_F);
        }
        // apply LN * gamma + beta, ReLU, bf16 -> hbuf; one b128 write per (kh,nb)
        #pragma unroll
        for (int khl = 0; khl < 2; ++khl) {
            float2 gp[2][4];
            #pragma unroll
            for (int half = 0; half < 2; ++half) {
                int mh = 4 * w + 2 * khl + half;
                #pragma unroll
                for (int r = 0; r < 4; ++r)
                    gp[half][r] = *(const float2*)&gbuf[(16 * mh + 4 * g + r) * 2];
            }
            #pragma unroll
            for (int nb = 0; nb < 4; ++nb) {
                float v[8];
                #pragma unroll
                for (int half = 0; half < 2; ++half) {
                    int mhi = 2 * khl + half;
                    #pragma unroll
                    for (int r = 0; r < 4; ++r)
                        v[half * 4 + r] = fmaxf(fmaf((acc[mhi][nb][r] - mu_[nb]) * rs_[nb],
                                                     gp[half][r].x, gp[half][r].y), 0.f);
                }
                uint4 q;
                q.x = pk2(v[0], v[1]); q.y = pk2(v[2], v[3]);
                q.z = pk2(v[4], v[5]); q.w = pk2(v[6], v[7]);
                int kh = 2 * w + khl;
                *reinterpret_cast<uint4*>(&hbuf[((kh * 4 + nb) * 64 + lane) * 8]) = q;
            }
        }
    };

    // mm2 (out^T = W2^T h^T) -> kreg ; W2 frags streamed from L2
    auto do_mm2 = [&]() {
        f32x4 bv = *(const f32x4*)&b2b[16 * w + 4 * g];
        #pragma unroll
        for (int nb = 0; nb < 4; ++nb) kreg[nb] = bv;
        #pragma unroll
        for (int kh = 0; kh < 16; ++kh) {
            bf16x8 Ah = w2v[(w * 16 + kh) * 64 + lane];
            bf16x8 Bf[4];
            #pragma unroll
            for (int nb = 0; nb < 4; ++nb)
                Bf[nb] = *(const bf16x8*)&hbuf[((kh * 4 + nb) * 64 + lane) * 8];
            #pragma unroll
            for (int nb = 0; nb < 4; ++nb)
                kreg[nb] = __builtin_amdgcn_mfma_f32_16x16x32_bf16(Ah, Bf[nb], kreg[nb], 0, 0, 0);
        }
    };

    auto f_eval = [&](float c) {
        build_xin(c);
        __syncthreads();
        do_mm1_ln();
        __syncthreads();
        do_mm2();
    };

    for (int s = 0; s < 20; ++s) {
        #pragma unroll
        for (int nb = 0; nb < 4; ++nb) acck[nb] = (f32x4)0.0f;

        f_eval(0.0f);
        #pragma unroll
        for (int nb = 0; nb < 4; ++nb) acck[nb] += kreg[nb];
        f_eval(0.5f * DT_F);
        #pragma unroll
        for (int nb = 0; nb < 4; ++nb) acck[nb] += kreg[nb] * 2.0f;
        f_eval(0.5f * DT_F);
        #pragma unroll
        for (int nb = 0; nb < 4; ++nb) acck[nb] += kreg[nb] * 2.0f;
        f_eval(DT_F);
        #pragma unroll
        for (int nb = 0; nb < 4; ++nb) {
            acck[nb] += kreg[nb];
            xreg[nb] += acck[nb] * (DT_F / 6.0f);
        }

        if (s >= 10 && (s & 1)) {
            // regularization eval at post-step states 12,14,16,18,20
            f_eval(0.0f);
            float amax[4] = {0,0,0,0};
            #pragma unroll
            for (int nb = 0; nb < 4; ++nb)
                #pragma unroll
                for (int r = 0; r < 4; ++r)
                    amax[nb] = fmaxf(amax[nb], fabsf(kreg[nb][r]));
            #pragma unroll
            for (int nb = 0; nb < 4; ++nb) {
                amax[nb] = fmaxf(amax[nb], __shfl_xor(amax[nb], 16));
                amax[nb] = fmaxf(amax[nb], __shfl_xor(amax[nb], 32));
            }
            if (lane < 16) {
                #pragma unroll
                for (int nb = 0; nb < 4; ++nb) rmx[(w * 4 + nb) * 16 + l15] = amax[nb];
            }
            __syncthreads();
            float rmax_[4];
            #pragma unroll
            for (int nb = 0; nb < 4; ++nb) {
                float m = rmx[(0 * 4 + nb) * 16 + l15];
                #pragma unroll
                for (int ww = 1; ww < 8; ++ww) m = fmaxf(m, rmx[(ww * 4 + nb) * 16 + l15]);
                rmax_[nb] = m;
            }
            float se[4] = {0,0,0,0}, sa[4] = {0,0,0,0};
            #pragma unroll
            for (int nb = 0; nb < 4; ++nb)
                #pragma unroll
                for (int r = 0; r < 4; ++r) {
                    float a = fabsf(kreg[nb][r]);
                    float e = __expf(a - rmax_[nb]);
                    se[nb] += e; sa[nb] = fmaf(a, e, sa[nb]);
                }
            #pragma unroll
            for (int nb = 0; nb < 4; ++nb) {
                se[nb] += __shfl_xor(se[nb], 16); se[nb] += __shfl_xor(se[nb], 32);
                sa[nb] += __shfl_xor(sa[nb], 16); sa[nb] += __shfl_xor(sa[nb], 32);
            }
            if (lane < 16) {
                #pragma unroll
                for (int nb = 0; nb < 4; ++nb) {
                    lnb[((w * 4 + nb) * 16 + l15) * 2 + 0] = se[nb];
                    lnb[((w * 4 + nb) * 16 + l15) * 2 + 1] = sa[nb];
                }
            }
            __syncthreads();
            if (w == 0) {
                // lane covers row 16*g + l15 (nb = g)
                float nse = 0.f, nsa = 0.f;
                #pragma unroll
                for (int ww = 0; ww < 8; ++ww) {
                    nse += lnb[((ww * 4 + g) * 16 + l15) * 2 + 0];
                    nsa += lnb[((ww * 4 + g) * 16 + l15) * 2 + 1];
                }
                float nrm = nsa / nse;
                #pragma unroll
                for (int m = 1; m < 64; m <<= 1) nrm += __shfl_xor(nrm, m);
                if (lane == 0) regtot += nrm;
            }
            __syncthreads();
        }
    }

    #pragma unroll
    for (int nb = 0; nb < 4; ++nb) {
        int brow = row0 + 16 * nb + l15;
        int ucol = 16 * w + 4 * g;
        *(f32x4*)&out[brow * 128 + ucol] = xreg[nb];
    }
    if (t == 0) regPart[blockIdx.x] = regtot;
}

__global__ __launch_bounds__(64)
void finalize_reg(const float* __restrict__ regPart, float* __restrict__ outReg)
{
    int t = threadIdx.x;
    float s = regPart[t] + regPart[t + 64] + regPart[t + 128] + regPart[t + 192];
    #pragma unroll
    for (int m = 1; m < 64; m <<= 1) s += __shfl_xor(s, m);
    if (t == 0) outReg[0] = s * (1.0f / (5.0f * 16384.0f));
}

extern "C" void kernel_launch(void* const* d_in, const int* in_sizes, int n_in,
                              void* d_out, int out_size, void* d_ws, size_t ws_size,
                              hipStream_t stream)
{
    (void)in_sizes; (void)n_in; (void)out_size; (void)ws_size;
    const float* x0    = (const float*)d_in[0];
    const float* W1    = (const float*)d_in[1];
    const float* b1    = (const float*)d_in[2];
    const float* gamma = (const float*)d_in[3];
    const float* beta  = (const float*)d_in[4];
    const float* W2    = (const float*)d_in[5];
    const float* b2    = (const float*)d_in[6];
    float* out = (float*)d_out;

    ushort_t* w1p = (ushort_t*)d_ws;                       // 128 KB
    ushort_t* w2p = w1p + 65536;                           // 128 KB
    float* regPart = (float*)((char*)d_ws + 262144);       // 1 KB

    pack_weights<<<64, 256, 0, stream>>>(W1, W2, w1p, w2p);
    node_ode<<<256, 512, 94720, stream>>>(x0, gamma, beta, b1, b2, w1p, w2p, out, regPart);
    finalize_reg<<<1, 64, 0, stream>>>(regPart, out + 2097152);
}